// Round 1
// baseline (85.354 us; speedup 1.0000x reference)
//
#include <hip/hip_runtime.h>

// BinsChamferLoss: L=4 scales, N=4 batch, P1=257 edges -> P=256 centers,
// depth maps 240x320 -> M=76800 points per batch element. Output: scalar loss.
//
// loss = sum_l mean_n [ mean_p min_validy (c-y)^2  +  (1/cnt_n) sum_validy min_p (c-y)^2 ]
//
// Track min|c-y| (2 VALU/pair: v_sub + v_min with abs modifier), square at the end —
// exact vs reference since fp32 squaring is monotone in |x|.

#define NSCALES 4
#define NBATCH  4
#define NEDGES  257
#define NP      256
#define NM      76800
#define CHUNK   512
#define NCHUNK  (NM / CHUNK)          // 150
#define BLOCK   256
#define NCENT   (NSCALES * NP)        // 1024
#define BIGF    1e10f

__global__ __launch_bounds__(BLOCK) void bcl_init(float* __restrict__ minabs,
                                                  float* __restrict__ sumy,
                                                  unsigned int* __restrict__ cnt) {
    int t = blockIdx.x * blockDim.x + threadIdx.x;
    if (t < NSCALES * NBATCH * NP) minabs[t] = BIGF;
    if (t < NSCALES * NBATCH)      sumy[t]   = 0.0f;
    if (t < NBATCH)                cnt[t]    = 0u;
}

__global__ __launch_bounds__(BLOCK) void bcl_main(const float* __restrict__ bins,
                                                  const float* __restrict__ depth,
                                                  float* __restrict__ minabs,
                                                  float* __restrict__ sumy,
                                                  unsigned int* __restrict__ cnt) {
    __shared__ float sY[CHUNK];          // y chunk (invalid -> 3e9 sentinel)
    __shared__ float sC[NCENT];          // centers, all 4 scales for batch n
    __shared__ float redS[BLOCK / 64][NSCALES];
    __shared__ unsigned int redC[BLOCK / 64];

    const int b = blockIdx.x;
    const int n = b / NCHUNK;
    const int chunk = b - n * NCHUNK;
    const int t = threadIdx.x;

    // --- stage y chunk (sentinel out invalid points) ---
    const float* yp = depth + n * NM + chunk * CHUNK;
#pragma unroll
    for (int k = 0; k < CHUNK / BLOCK; ++k) {
        float v = yp[t + k * BLOCK];
        sY[t + k * BLOCK] = (v >= 0.001f) ? v : 3e9f;
    }
    // --- stage centers: i = l*NP + p ---
#pragma unroll
    for (int k = 0; k < NCENT / BLOCK; ++k) {
        int i = t + k * BLOCK;
        int l = i >> 8;
        int p = i & (NP - 1);
        const float* be = bins + (l * NBATCH + n) * NEDGES + p;
        sC[i] = 0.5f * (be[0] + be[1]);
    }
    __syncthreads();

    // ================= direction A: per-center min over y chunk =================
    // thread t owns center p=t of each scale l (index t + l*256 in sC)
    float ca[NSCALES], ma[NSCALES];
#pragma unroll
    for (int k = 0; k < NSCALES; ++k) { ca[k] = sC[t + k * BLOCK]; ma[k] = BIGF; }

    const float4* sY4 = (const float4*)sY;
#pragma unroll 2
    for (int q = 0; q < CHUNK / 4; ++q) {
        float4 yv = sY4[q];
#pragma unroll
        for (int k = 0; k < NSCALES; ++k) {
            ma[k] = fminf(ma[k], fabsf(ca[k] - yv.x));
            ma[k] = fminf(ma[k], fabsf(ca[k] - yv.y));
            ma[k] = fminf(ma[k], fabsf(ca[k] - yv.z));
            ma[k] = fminf(ma[k], fabsf(ca[k] - yv.w));
        }
    }
    // non-negative floats: int-compare == float-compare
#pragma unroll
    for (int k = 0; k < NSCALES; ++k)
        atomicMin((int*)(minabs + (k * NBATCH + n) * NP + t), __float_as_int(ma[k]));

    // ================= direction B: per-y min over all centers =================
    // thread t owns y points j = t, t+256
    float yb0 = sY[t];
    float yb1 = sY[t + BLOCK];
    const bool v0 = yb0 < 2.0f, v1 = yb1 < 2.0f;

    float suml[NSCALES];
    const float4* sC4 = (const float4*)sC;
#pragma unroll
    for (int l = 0; l < NSCALES; ++l) {
        float m0 = BIGF, m1 = BIGF;
#pragma unroll 4
        for (int q = 0; q < NP / 4; ++q) {
            float4 c = sC4[l * (NP / 4) + q];
            m0 = fminf(m0, fabsf(c.x - yb0));  m1 = fminf(m1, fabsf(c.x - yb1));
            m0 = fminf(m0, fabsf(c.y - yb0));  m1 = fminf(m1, fabsf(c.y - yb1));
            m0 = fminf(m0, fabsf(c.z - yb0));  m1 = fminf(m1, fabsf(c.z - yb1));
            m0 = fminf(m0, fabsf(c.w - yb0));  m1 = fminf(m1, fabsf(c.w - yb1));
        }
        float s = 0.0f;
        if (v0) s += m0 * m0;
        if (v1) s += m1 * m1;
        suml[l] = s;
    }
    unsigned int c = (v0 ? 1u : 0u) + (v1 ? 1u : 0u);

    // --- block reduction (wave shuffle + LDS across 4 waves) ---
#pragma unroll
    for (int off = 32; off; off >>= 1) {
#pragma unroll
        for (int l = 0; l < NSCALES; ++l) suml[l] += __shfl_down(suml[l], off);
        c += __shfl_down(c, off);
    }
    const int wv = t >> 6;
    if ((t & 63) == 0) {
#pragma unroll
        for (int l = 0; l < NSCALES; ++l) redS[wv][l] = suml[l];
        redC[wv] = c;
    }
    __syncthreads();
    if (t < NSCALES) {
        float s = redS[0][t] + redS[1][t] + redS[2][t] + redS[3][t];
        atomicAdd(&sumy[t * NBATCH + n], s);
    }
    if (t == 0) {
        unsigned int cc = redC[0] + redC[1] + redC[2] + redC[3];
        atomicAdd(&cnt[n], cc);
    }
}

__global__ __launch_bounds__(BLOCK) void bcl_final(const float* __restrict__ minabs,
                                                   const float* __restrict__ sumy,
                                                   const unsigned int* __restrict__ cnt,
                                                   float* __restrict__ out) {
    __shared__ float red[BLOCK / 64];
    int t = threadIdx.x;
    float s = 0.0f;
#pragma unroll
    for (int k = 0; k < (NSCALES * NBATCH * NP) / BLOCK; ++k) {
        float m = minabs[t + k * BLOCK];
        s += m * m;
    }
#pragma unroll
    for (int off = 32; off; off >>= 1) s += __shfl_down(s, off);
    if ((t & 63) == 0) red[t >> 6] = s;
    __syncthreads();
    if (t == 0) {
        float S = red[0] + red[1] + red[2] + red[3];     // sum of all minx^2
        float lossA = S / (float)NP;                     // will be /N below
        float lossB = 0.0f;
#pragma unroll
        for (int i = 0; i < NSCALES * NBATCH; ++i)
            lossB += sumy[i] / (float)cnt[i & (NBATCH - 1)];
        out[0] = (lossA + lossB) / (float)NBATCH;
    }
}

extern "C" void kernel_launch(void* const* d_in, const int* in_sizes, int n_in,
                              void* d_out, int out_size, void* d_ws, size_t ws_size,
                              hipStream_t stream) {
    const float* bins  = (const float*)d_in[0];   // [L, N, 257] f32
    const float* depth = (const float*)d_in[1];   // [N, 240, 320] f32

    float* minabs = (float*)d_ws;                              // L*N*P floats
    float* sumy   = minabs + NSCALES * NBATCH * NP;            // L*N floats
    unsigned int* cnt = (unsigned int*)(sumy + NSCALES * NBATCH);  // N uints

    bcl_init<<<(NSCALES * NBATCH * NP + BLOCK - 1) / BLOCK, BLOCK, 0, stream>>>(minabs, sumy, cnt);
    bcl_main<<<NBATCH * NCHUNK, BLOCK, 0, stream>>>(bins, depth, minabs, sumy, cnt);
    bcl_final<<<1, BLOCK, 0, stream>>>(minabs, sumy, cnt, (float*)d_out);
}